// Round 2
// baseline (134.038 us; speedup 1.0000x reference)
//
#include <hip/hip_runtime.h>
#include <math.h>
#include <stdint.h>

#define BB 16
#define DD 96
#define TT 512
#define HH 1024
#define NROW (BB*DD)
#define KT2 (HH/32)   // 32 k-tiles of 32 for gemm2

typedef __attribute__((ext_vector_type(4))) float floatx4;
typedef __attribute__((ext_vector_type(8))) short short8;

// ---------------- ws layout (bytes) ----------------
// x fp32 (3MB) | A fp32 (576KB, dead after k_attn) aliased by hfrag bf16 (3MB)
// | w1bf (1MB) | w2bf (1MB) | ps (48KB) | ps2 (48KB) | scsh (768B)
#define WSOFF_X     0u
#define WSOFF_A     3145728u
#define WSOFF_HFRAG WSOFF_A
#define WSOFF_W1BF  6291456u
#define WSOFF_W2BF  7340032u
#define WSOFF_PS    8388608u
#define WSOFF_PS2   8437760u
#define WSOFF_SCSH  8486912u

__device__ __forceinline__ uint16_t f2bf(float v) {
    uint32_t u = __float_as_uint(v);
    uint32_t r = 0x7fffu + ((u >> 16) & 1u);
    return (uint16_t)((u + r) >> 16);
}

// K1: blocks 0..15: per-batch rowsum + softmax -> A.  blocks 16..511: weight swizzle.
__global__ __launch_bounds__(256) void k_pre(const float* __restrict__ residual,
                                             const float* __restrict__ W1,
                                             const float* __restrict__ W2,
                                             float* __restrict__ A,
                                             uint16_t* __restrict__ w1bf,
                                             uint16_t* __restrict__ w2bf) {
    __shared__ float sl[DD];
    const int bid = blockIdx.x;
    const int tid = threadIdx.x;
    const int wave = tid >> 6;
    const int lane = tid & 63;
    const int q = lane >> 4, l15 = lane & 15;

    if (bid < BB) {
        #pragma unroll
        for (int rr = 0; rr < 24; ++rr) {
            int i = wave*24 + rr;
            const float* p = residual + ((size_t)bid*DD + i)*TT;
            float acc = 0.f;
            #pragma unroll
            for (int u = 0; u < TT/64; ++u) acc += p[lane + u*64];
            #pragma unroll
            for (int o = 32; o > 0; o >>= 1) acc += __shfl_down(acc, o, 64);
            if (lane == 0) sl[i] = acc;
        }
        __syncthreads();
        if (tid < DD) {
            const float c = 1.0f / (512.0f * 22.627416997969522f);  // T^-1.5
            float si = sl[tid] * c;
            float m = -1e30f;
            for (int j = 0; j < DD; ++j) m = fmaxf(m, si * sl[j]);
            float sum = 0.f;
            for (int j = 0; j < DD; ++j) sum += __expf(si * sl[j] - m);
            float inv = 1.0f / sum;
            float* Ao = A + ((size_t)bid*DD + tid)*DD;
            for (int j = 0; j < DD; ++j) Ao[j] = __expf(si * sl[j] - m) * inv;
        }
    } else {
        int wgid = (bid - BB)*4 + wave;
        const int nw = (512 - BB)*4;
        for (int u = wgid; u < 2048; u += nw) {
            const float* W; uint16_t* ob; int KT, N, b;
            if (u < 1024) { W = W1; ob = w1bf; KT = 16; N = 1024; b = u; }
            else          { W = W2; ob = w2bf; KT = 32; N = 512;  b = u - 1024; }
            int tile_n = b / KT, tile_k = b % KT;
            const float* src = W + (size_t)(tile_k*32 + q*8)*N + tile_n*16 + l15;
            uint16_t tmp[8];
            #pragma unroll
            for (int j = 0; j < 8; ++j) tmp[j] = f2bf(src[(size_t)j*N]);
            uint16_t* dst = ob + ((size_t)b*64 + lane)*8;
            *reinterpret_cast<ushort4*>(dst)     = *reinterpret_cast<ushort4*>(&tmp[0]);
            *reinterpret_cast<ushort4*>(dst + 4) = *reinterpret_cast<ushort4*>(&tmp[4]);
        }
    }
}

// K2: x = A@r + r, with BN partial sums (per (d, b, chunk); no atomics).
__global__ __launch_bounds__(256) void k_attn(const float* __restrict__ residual,
                                              const float* __restrict__ A,
                                              float* __restrict__ x,
                                              float* __restrict__ ps,
                                              float* __restrict__ ps2) {
    __shared__ float rlds[DD*64];
    const int u = blockIdx.x;           // 512 = 16 b * 8 chunk * 4 ig
    const int b = u >> 5, chunk = (u >> 2) & 7, ig = u & 3;
    const int tid = threadIdx.x;
    const int wave = tid >> 6;
    const int lane = tid & 63;

    const float4* rb4 = reinterpret_cast<const float4*>(residual + (size_t)b*DD*TT);
    float4* rl4 = reinterpret_cast<float4*>(rlds);
    #pragma unroll
    for (int s = 0; s < 6; ++s) {
        int idx = tid + s*256;
        int i = idx >> 4, t4 = idx & 15;
        rl4[idx] = rb4[(size_t)i*(TT/4) + chunk*16 + t4];
    }
    __syncthreads();

    int i0 = ig*24 + wave*6;
    const float* Ab = A + ((size_t)b*DD + i0)*DD;
    float acc[6];
    #pragma unroll
    for (int rr = 0; rr < 6; ++rr) acc[rr] = rlds[(i0+rr)*64 + lane];
    #pragma unroll 4
    for (int j4 = 0; j4 < DD/4; ++j4) {
        float4 a[6];
        #pragma unroll
        for (int rr = 0; rr < 6; ++rr)
            a[rr] = *reinterpret_cast<const float4*>(Ab + rr*DD + j4*4);
        float rv[4];
        #pragma unroll
        for (int uu = 0; uu < 4; ++uu) rv[uu] = rlds[(j4*4+uu)*64 + lane];
        #pragma unroll
        for (int rr = 0; rr < 6; ++rr) {
            acc[rr] = fmaf(a[rr].x, rv[0], acc[rr]);
            acc[rr] = fmaf(a[rr].y, rv[1], acc[rr]);
            acc[rr] = fmaf(a[rr].z, rv[2], acc[rr]);
            acc[rr] = fmaf(a[rr].w, rv[3], acc[rr]);
        }
    }
    #pragma unroll
    for (int rr = 0; rr < 6; ++rr) {
        float v = acc[rr];
        x[((size_t)b*DD + i0 + rr)*TT + chunk*64 + lane] = v;
        float s1 = v, s2 = v*v;
        #pragma unroll
        for (int o = 32; o > 0; o >>= 1) {
            s1 += __shfl_down(s1, o, 64);
            s2 += __shfl_down(s2, o, 64);
        }
        if (lane == 0) {
            int d = i0 + rr;
            ps [d*128 + b*8 + chunk] = s1;
            ps2[d*128 + b*8 + chunk] = s2;
        }
    }
}

// K3: per-block BN finalize (from partials) + gemm1 with inline BN on A-fragments.
// grid 384 = 96 mtiles * 4 nq; block = 256.  M=16, N=256 per block.
__global__ __launch_bounds__(256) void k_gemm1(const float* __restrict__ x,
                                               const float* __restrict__ ps,
                                               const float* __restrict__ ps2,
                                               const float* __restrict__ bng,
                                               const float* __restrict__ bnb,
                                               const uint16_t* __restrict__ w1bf,
                                               const float* __restrict__ b1,
                                               uint16_t* __restrict__ hfrag,
                                               float* __restrict__ scsh) {
    __shared__ __align__(16) char SM[27136];
    uint16_t* fragA = (uint16_t*)SM;            // [16][64][8] = 16384B
    uint16_t* cs    = (uint16_t*)(SM + 16384);  // [16][264]   = 8448B
    float*    fin   = (float*)(SM + 24832);     // [384]       = 1536B
    float*    scs   = (float*)(SM + 26368);     // [192]       = 768B
    const int bid = blockIdx.x;
    const int tid = threadIdx.x;
    const int wave = tid >> 6;
    const int lane = tid & 63;
    const int q = lane >> 4, l15 = lane & 15;

    // BN finalize (each block redundantly; 98KB from L2)
    if (tid < 192) {
        int d = tid >> 1, h = tid & 1;
        const float4* p1 = reinterpret_cast<const float4*>(ps  + d*128 + h*64);
        const float4* p2 = reinterpret_cast<const float4*>(ps2 + d*128 + h*64);
        float a1 = 0.f, a2 = 0.f;
        #pragma unroll
        for (int j = 0; j < 16; ++j) {
            float4 v = p1[j]; a1 += v.x+v.y+v.z+v.w;
            float4 w = p2[j]; a2 += w.x+w.y+w.z+w.w;
        }
        fin[tid*2]   = a1;
        fin[tid*2+1] = a2;
    }
    __syncthreads();
    if (tid < DD) {
        float s1 = fin[tid*4]   + fin[tid*4+2];
        float s2 = fin[tid*4+1] + fin[tid*4+3];
        const float invn = 1.0f / (float)(BB*TT);
        float mu  = s1 * invn;
        float var = s2 * invn - mu*mu;
        float rs  = rsqrtf(var + 1e-5f);
        float scv = rs * bng[tid];
        float shv = bnb[tid] - mu*scv;
        scs[tid]      = scv;
        scs[DD + tid] = shv;
        if (bid == 0) { scsh[tid] = scv; scsh[DD + tid] = shv; }   // for k_gemm2
    }
    __syncthreads();

    const int mtile = bid >> 2, nq = bid & 3;
    // build bf16 A-fragments (BN applied inline)
    #pragma unroll
    for (int r4 = 0; r4 < 4; ++r4) {
        int pi = tid + r4*256;
        int kk = pi >> 6, pl = pi & 63;
        int pq = pl >> 4, pr = pl & 15;
        int row = mtile*16 + pr;
        int d = row % DD;
        float scv = scs[d], shv = scs[DD + d];
        const float* xp = x + (size_t)row*TT + kk*32 + pq*8;
        float4 v0 = *reinterpret_cast<const float4*>(xp);
        float4 v1 = *reinterpret_cast<const float4*>(xp + 4);
        ushort4 o0, o1;
        o0.x = f2bf(v0.x*scv + shv); o0.y = f2bf(v0.y*scv + shv);
        o0.z = f2bf(v0.z*scv + shv); o0.w = f2bf(v0.w*scv + shv);
        o1.x = f2bf(v1.x*scv + shv); o1.y = f2bf(v1.y*scv + shv);
        o1.z = f2bf(v1.z*scv + shv); o1.w = f2bf(v1.w*scv + shv);
        uint16_t* fp = fragA + ((size_t)kk*64 + pl)*8;
        *reinterpret_cast<ushort4*>(fp)     = o0;
        *reinterpret_cast<ushort4*>(fp + 4) = o1;
    }
    __syncthreads();

    int n0 = nq*256 + wave*64;
    floatx4 acc4[4] = {};
    #pragma unroll
    for (int kk = 0; kk < 16; ++kk) {
        short8 a = *reinterpret_cast<const short8*>(fragA + (kk*64 + lane)*8);
        #pragma unroll
        for (int nf = 0; nf < 4; ++nf) {
            int ct = (n0 >> 4) + nf;
            short8 bfr = *reinterpret_cast<const short8*>(
                w1bf + ((size_t)(ct*16 + kk)*64 + lane)*8);
            acc4[nf] = __builtin_amdgcn_mfma_f32_16x16x32_bf16(a, bfr, acc4[nf], 0, 0, 0);
        }
    }
    #pragma unroll
    for (int nf = 0; nf < 4; ++nf) {
        int coll = wave*64 + nf*16 + l15;
        float bias = b1[nq*256 + coll];
        #pragma unroll
        for (int r = 0; r < 4; ++r) {
            float v = acc4[nf][r] + bias;
            float gl = 0.5f * v * (1.0f + erff(v * 0.7071067811865475f));
            cs[(q*4 + r)*264 + coll] = f2bf(gl);
        }
    }
    __syncthreads();
    #pragma unroll
    for (int cc = 0; cc < 2; ++cc) {
        int c = wave*2 + cc;
        const uint4* srcp = reinterpret_cast<const uint4*>(cs + l15*264 + c*32 + q*8);
        size_t chunk = (size_t)mtile*KT2 + nq*8 + c;
        reinterpret_cast<uint4*>(hfrag)[chunk*64 + lane] = *srcp;
    }
}

// K4: gemm2 + bias + BN(x) residual (fp32) + fused LayerNorm, all in registers.
// grid 96; block 256.  M=16, full N=512 (wave w: cols w*128..w*128+127).
__global__ __launch_bounds__(256) void k_gemm2(const uint16_t* __restrict__ hfrag,
                                               const uint16_t* __restrict__ w2bf,
                                               const float* __restrict__ b2,
                                               const float* __restrict__ x,
                                               const float* __restrict__ scsh,
                                               const float* __restrict__ lng,
                                               const float* __restrict__ lnb,
                                               float* __restrict__ out) {
    __shared__ float lnred[128];   // [4 waves][16 rows][2]
    const int mtile = blockIdx.x;
    const int tid = threadIdx.x;
    const int wave = tid >> 6;
    const int lane = tid & 63;
    const int q = lane >> 4, l15 = lane & 15;
    const int m0 = mtile*16;
    const int n0 = wave*128;

    floatx4 acc[8] = {};
    const uint16_t* ap = hfrag + ((size_t)mtile*KT2*64 + lane)*8;
    #pragma unroll
    for (int kk = 0; kk < 32; ++kk) {
        short8 a = *reinterpret_cast<const short8*>(ap + kk*512);
        #pragma unroll
        for (int nf = 0; nf < 8; ++nf) {
            int ct = (n0 >> 4) + nf;
            short8 bfr = *reinterpret_cast<const short8*>(
                w2bf + ((size_t)(ct*32 + kk)*64 + lane)*8);
            acc[nf] = __builtin_amdgcn_mfma_f32_16x16x32_bf16(a, bfr, acc[nf], 0, 0, 0);
        }
    }
    // v = acc + b2 + BN(x); keep in registers, accumulate LN partials
    float s_pt[4]  = {0.f,0.f,0.f,0.f};
    float s2_pt[4] = {0.f,0.f,0.f,0.f};
    #pragma unroll
    for (int r = 0; r < 4; ++r) {
        int row = m0 + q*4 + r;
        int d = row % DD;
        float scv = scsh[d], shv = scsh[DD + d];
        #pragma unroll
        for (int nf = 0; nf < 8; ++nf) {
            int col = n0 + nf*16 + l15;
            float v = acc[nf][r] + b2[col] + x[(size_t)row*TT + col]*scv + shv;
            acc[nf][r] = v;
            s_pt[r]  += v;
            s2_pt[r] += v*v;
        }
    }
    #pragma unroll
    for (int o = 1; o < 16; o <<= 1) {
        #pragma unroll
        for (int r = 0; r < 4; ++r) {
            s_pt[r]  += __shfl_xor(s_pt[r],  o, 64);
            s2_pt[r] += __shfl_xor(s2_pt[r], o, 64);
        }
    }
    if (l15 == 0) {
        #pragma unroll
        for (int r = 0; r < 4; ++r) {
            lnred[(wave*16 + q*4 + r)*2]     = s_pt[r];
            lnred[(wave*16 + q*4 + r)*2 + 1] = s2_pt[r];
        }
    }
    __syncthreads();
    #pragma unroll
    for (int r = 0; r < 4; ++r) {
        int rloc = q*4 + r;
        float s1 = lnred[rloc*2]   + lnred[(16+rloc)*2]   + lnred[(32+rloc)*2]   + lnred[(48+rloc)*2];
        float s2 = lnred[rloc*2+1] + lnred[(16+rloc)*2+1] + lnred[(32+rloc)*2+1] + lnred[(48+rloc)*2+1];
        const float invT = 1.0f / (float)TT;
        float mu  = s1 * invT;
        float var = s2 * invT - mu*mu;
        float rs  = rsqrtf(var + 1e-5f);
        int row = m0 + rloc;
        #pragma unroll
        for (int nf = 0; nf < 8; ++nf) {
            int col = n0 + nf*16 + l15;
            out[(size_t)row*TT + col] = (acc[nf][r] - mu)*rs*lng[col] + lnb[col];
        }
    }
}

extern "C" void kernel_launch(void* const* d_in, const int* in_sizes, int n_in,
                              void* d_out, int out_size, void* d_ws, size_t ws_size,
                              hipStream_t stream) {
    (void)in_sizes; (void)n_in; (void)out_size; (void)ws_size;
    const float* residual = (const float*)d_in[0];
    const float* bng = (const float*)d_in[1];
    const float* bnb = (const float*)d_in[2];
    const float* lng = (const float*)d_in[3];
    const float* lnb = (const float*)d_in[4];
    const float* W1  = (const float*)d_in[5];
    const float* b1  = (const float*)d_in[6];
    const float* W2  = (const float*)d_in[7];
    const float* b2  = (const float*)d_in[8];
    float* out = (float*)d_out;
    char* ws = (char*)d_ws;
    float*    x     = (float*)(ws + WSOFF_X);
    float*    A     = (float*)(ws + WSOFF_A);
    uint16_t* hfrag = (uint16_t*)(ws + WSOFF_HFRAG);
    uint16_t* w1bf  = (uint16_t*)(ws + WSOFF_W1BF);
    uint16_t* w2bf  = (uint16_t*)(ws + WSOFF_W2BF);
    float*    ps    = (float*)(ws + WSOFF_PS);
    float*    ps2   = (float*)(ws + WSOFF_PS2);
    float*    scsh  = (float*)(ws + WSOFF_SCSH);

    k_pre  <<<512, 256, 0, stream>>>(residual, W1, W2, A, w1bf, w2bf);
    k_attn <<<512, 256, 0, stream>>>(residual, A, x, ps, ps2);
    k_gemm1<<<384, 256, 0, stream>>>(x, ps, ps2, bng, bnb, w1bf, b1, hfrag, scsh);
    k_gemm2<<<96, 256, 0, stream>>>(hfrag, w2bf, b2, x, scsh, lng, lnb, out);
}

// Round 3
// 131.432 us; speedup vs baseline: 1.0198x; 1.0198x over previous
//
#include <hip/hip_runtime.h>
#include <math.h>
#include <stdint.h>

#define BB 16
#define DD 96
#define TT 512
#define HH 1024
#define NROW (BB*DD)
#define KT2 (HH/32)   // 32 k-tiles of 32 for gemm2

typedef __attribute__((ext_vector_type(4))) float floatx4;
typedef __attribute__((ext_vector_type(8))) short short8;

// ---------------- ws layout (bytes) ----------------
// x fp32 (3MB) | A fp32 (576KB, dead after k_attn) aliased by hfrag bf16 (3MB)
// | w1bf (1MB) | w2bf (1MB) | ps (48KB) | ps2 (48KB) | scsh (768B)
#define WSOFF_X     0u
#define WSOFF_A     3145728u
#define WSOFF_HFRAG WSOFF_A
#define WSOFF_W1BF  6291456u
#define WSOFF_W2BF  7340032u
#define WSOFF_PS    8388608u
#define WSOFF_PS2   8437760u
#define WSOFF_SCSH  8486912u

__device__ __forceinline__ uint16_t f2bf(float v) {
    uint32_t u = __float_as_uint(v);
    uint32_t r = 0x7fffu + ((u >> 16) & 1u);
    return (uint16_t)((u + r) >> 16);
}

// K1: blocks 0..15: per-batch rowsum + softmax -> A.  blocks 16..511: weight swizzle.
__global__ __launch_bounds__(256) void k_pre(const float* __restrict__ residual,
                                             const float* __restrict__ W1,
                                             const float* __restrict__ W2,
                                             float* __restrict__ A,
                                             uint16_t* __restrict__ w1bf,
                                             uint16_t* __restrict__ w2bf) {
    __shared__ float sl[DD];
    const int bid = blockIdx.x;
    const int tid = threadIdx.x;
    const int wave = tid >> 6;
    const int lane = tid & 63;
    const int q = lane >> 4, l15 = lane & 15;

    if (bid < BB) {
        #pragma unroll
        for (int rr = 0; rr < 24; ++rr) {
            int i = wave*24 + rr;
            const float* p = residual + ((size_t)bid*DD + i)*TT;
            float acc = 0.f;
            #pragma unroll
            for (int u = 0; u < TT/64; ++u) acc += p[lane + u*64];
            #pragma unroll
            for (int o = 32; o > 0; o >>= 1) acc += __shfl_down(acc, o, 64);
            if (lane == 0) sl[i] = acc;
        }
        __syncthreads();
        if (tid < DD) {
            const float c = 1.0f / (512.0f * 22.627416997969522f);  // T^-1.5
            float si = sl[tid] * c;
            float m = -1e30f;
            for (int j = 0; j < DD; ++j) m = fmaxf(m, si * sl[j]);
            float sum = 0.f;
            for (int j = 0; j < DD; ++j) sum += __expf(si * sl[j] - m);
            float inv = 1.0f / sum;
            float* Ao = A + ((size_t)bid*DD + tid)*DD;
            for (int j = 0; j < DD; ++j) Ao[j] = __expf(si * sl[j] - m) * inv;
        }
    } else {
        int wgid = (bid - BB)*4 + wave;
        const int nw = (512 - BB)*4;
        for (int u = wgid; u < 2048; u += nw) {
            const float* W; uint16_t* ob; int KT, N, b;
            if (u < 1024) { W = W1; ob = w1bf; KT = 16; N = 1024; b = u; }
            else          { W = W2; ob = w2bf; KT = 32; N = 512;  b = u - 1024; }
            int tile_n = b / KT, tile_k = b % KT;
            const float* src = W + (size_t)(tile_k*32 + q*8)*N + tile_n*16 + l15;
            uint16_t tmp[8];
            #pragma unroll
            for (int j = 0; j < 8; ++j) tmp[j] = f2bf(src[(size_t)j*N]);
            uint16_t* dst = ob + ((size_t)b*64 + lane)*8;
            *reinterpret_cast<ushort4*>(dst)     = *reinterpret_cast<ushort4*>(&tmp[0]);
            *reinterpret_cast<ushort4*>(dst + 4) = *reinterpret_cast<ushort4*>(&tmp[4]);
        }
    }
}

// K2: x = A@r + r, with BN partial sums (per (d, b, chunk); no atomics).
__global__ __launch_bounds__(256) void k_attn(const float* __restrict__ residual,
                                              const float* __restrict__ A,
                                              float* __restrict__ x,
                                              float* __restrict__ ps,
                                              float* __restrict__ ps2) {
    __shared__ float rlds[DD*64];
    const int u = blockIdx.x;           // 512 = 16 b * 8 chunk * 4 ig
    const int b = u >> 5, chunk = (u >> 2) & 7, ig = u & 3;
    const int tid = threadIdx.x;
    const int wave = tid >> 6;
    const int lane = tid & 63;

    const float4* rb4 = reinterpret_cast<const float4*>(residual + (size_t)b*DD*TT);
    float4* rl4 = reinterpret_cast<float4*>(rlds);
    #pragma unroll
    for (int s = 0; s < 6; ++s) {
        int idx = tid + s*256;
        int i = idx >> 4, t4 = idx & 15;
        rl4[idx] = rb4[(size_t)i*(TT/4) + chunk*16 + t4];
    }
    __syncthreads();

    int i0 = ig*24 + wave*6;
    const float* Ab = A + ((size_t)b*DD + i0)*DD;
    float acc[6];
    #pragma unroll
    for (int rr = 0; rr < 6; ++rr) acc[rr] = rlds[(i0+rr)*64 + lane];
    #pragma unroll 4
    for (int j4 = 0; j4 < DD/4; ++j4) {
        float4 a[6];
        #pragma unroll
        for (int rr = 0; rr < 6; ++rr)
            a[rr] = *reinterpret_cast<const float4*>(Ab + rr*DD + j4*4);
        float rv[4];
        #pragma unroll
        for (int uu = 0; uu < 4; ++uu) rv[uu] = rlds[(j4*4+uu)*64 + lane];
        #pragma unroll
        for (int rr = 0; rr < 6; ++rr) {
            acc[rr] = fmaf(a[rr].x, rv[0], acc[rr]);
            acc[rr] = fmaf(a[rr].y, rv[1], acc[rr]);
            acc[rr] = fmaf(a[rr].z, rv[2], acc[rr]);
            acc[rr] = fmaf(a[rr].w, rv[3], acc[rr]);
        }
    }
    #pragma unroll
    for (int rr = 0; rr < 6; ++rr) {
        float v = acc[rr];
        x[((size_t)b*DD + i0 + rr)*TT + chunk*64 + lane] = v;
        float s1 = v, s2 = v*v;
        #pragma unroll
        for (int o = 32; o > 0; o >>= 1) {
            s1 += __shfl_down(s1, o, 64);
            s2 += __shfl_down(s2, o, 64);
        }
        if (lane == 0) {
            int d = i0 + rr;
            ps [d*128 + b*8 + chunk] = s1;
            ps2[d*128 + b*8 + chunk] = s2;
        }
    }
}

// K3: per-block BN finalize + gemm1 with inline BN on A-fragments.
// grid (96, 4); block = 512 (8 waves).  M=16, N=256 per block, N=32 per wave.
__global__ __launch_bounds__(512) void k_gemm1(const float* __restrict__ x,
                                               const float* __restrict__ ps,
                                               const float* __restrict__ ps2,
                                               const float* __restrict__ bng,
                                               const float* __restrict__ bnb,
                                               const uint16_t* __restrict__ w1bf,
                                               const float* __restrict__ b1,
                                               uint16_t* __restrict__ hfrag,
                                               float* __restrict__ scsh) {
    __shared__ __align__(16) char SM[27136];
    uint16_t* fragA = (uint16_t*)SM;            // [16][64][8] = 16384B
    uint16_t* cs    = (uint16_t*)(SM + 16384);  // [16][264]   = 8448B
    float*    fin   = (float*)(SM + 24832);     // [384]
    float*    scs   = (float*)(SM + 26368);     // [192]
    const int mtile = blockIdx.x;
    const int nq    = blockIdx.y;
    const int tid = threadIdx.x;
    const int wave = tid >> 6;
    const int lane = tid & 63;
    const int q = lane >> 4, l15 = lane & 15;

    // BN finalize (each block redundantly; ~96KB from L2/L3)
    if (tid < 192) {
        int d = tid >> 1, h = tid & 1;
        const float4* p1 = reinterpret_cast<const float4*>(ps  + d*128 + h*64);
        const float4* p2 = reinterpret_cast<const float4*>(ps2 + d*128 + h*64);
        float a1 = 0.f, a2 = 0.f;
        #pragma unroll
        for (int j = 0; j < 16; ++j) {
            float4 v = p1[j]; a1 += v.x+v.y+v.z+v.w;
            float4 w = p2[j]; a2 += w.x+w.y+w.z+w.w;
        }
        fin[tid*2]   = a1;
        fin[tid*2+1] = a2;
    }
    __syncthreads();
    if (tid < DD) {
        float s1 = fin[tid*4]   + fin[tid*4+2];
        float s2 = fin[tid*4+1] + fin[tid*4+3];
        const float invn = 1.0f / (float)(BB*TT);
        float mu  = s1 * invn;
        float var = s2 * invn - mu*mu;
        float rs  = rsqrtf(var + 1e-5f);
        float scv = rs * bng[tid];
        float shv = bnb[tid] - mu*scv;
        scs[tid]      = scv;
        scs[DD + tid] = shv;
        if (mtile == 0 && nq == 0) { scsh[tid] = scv; scsh[DD + tid] = shv; }
    }
    __syncthreads();

    // build bf16 A-fragments (BN applied inline): 1024 writes of 8 bf16
    #pragma unroll
    for (int r4 = 0; r4 < 2; ++r4) {
        int pi = tid + r4*512;
        int kk = pi >> 6, pl = pi & 63;
        int pq = pl >> 4, pr = pl & 15;
        int row = mtile*16 + pr;
        int d = row % DD;
        float scv = scs[d], shv = scs[DD + d];
        const float* xp = x + (size_t)row*TT + kk*32 + pq*8;
        float4 v0 = *reinterpret_cast<const float4*>(xp);
        float4 v1 = *reinterpret_cast<const float4*>(xp + 4);
        ushort4 o0, o1;
        o0.x = f2bf(v0.x*scv + shv); o0.y = f2bf(v0.y*scv + shv);
        o0.z = f2bf(v0.z*scv + shv); o0.w = f2bf(v0.w*scv + shv);
        o1.x = f2bf(v1.x*scv + shv); o1.y = f2bf(v1.y*scv + shv);
        o1.z = f2bf(v1.z*scv + shv); o1.w = f2bf(v1.w*scv + shv);
        uint16_t* fp = fragA + ((size_t)kk*64 + pl)*8;
        *reinterpret_cast<ushort4*>(fp)     = o0;
        *reinterpret_cast<ushort4*>(fp + 4) = o1;
    }
    __syncthreads();

    const int n0 = nq*256 + wave*32;
    floatx4 acc4[2] = {};
    #pragma unroll
    for (int kk = 0; kk < 16; ++kk) {
        short8 a = *reinterpret_cast<const short8*>(fragA + (kk*64 + lane)*8);
        #pragma unroll
        for (int nf = 0; nf < 2; ++nf) {
            int ct = (n0 >> 4) + nf;
            short8 bfr = *reinterpret_cast<const short8*>(
                w1bf + ((size_t)(ct*16 + kk)*64 + lane)*8);
            acc4[nf] = __builtin_amdgcn_mfma_f32_16x16x32_bf16(a, bfr, acc4[nf], 0, 0, 0);
        }
    }
    #pragma unroll
    for (int nf = 0; nf < 2; ++nf) {
        int coll = wave*32 + nf*16 + l15;
        float bias = b1[nq*256 + coll];
        #pragma unroll
        for (int r = 0; r < 4; ++r) {
            float v = acc4[nf][r] + bias;
            float gl = 0.5f * v * (1.0f + erff(v * 0.7071067811865475f));
            cs[(q*4 + r)*264 + coll] = f2bf(gl);
        }
    }
    __syncthreads();
    {
        int c = wave;   // 8 waves -> 8 k-chunks of this block's 256-col slice
        const uint4* srcp = reinterpret_cast<const uint4*>(cs + l15*264 + c*32 + q*8);
        size_t chunk = (size_t)mtile*KT2 + nq*8 + c;
        reinterpret_cast<uint4*>(hfrag)[chunk*64 + lane] = *srcp;
    }
}

// K4: gemm2 + bias + BN(x) residual + fused LayerNorm.
// grid 96; block 1024 (16 waves, 4/SIMD).  M=16, N=512; N=32 per wave.
// A-slice (32KB) staged in LDS once.
__global__ __launch_bounds__(1024) void k_gemm2(const uint16_t* __restrict__ hfrag,
                                                const uint16_t* __restrict__ w2bf,
                                                const float* __restrict__ b2,
                                                const float* __restrict__ x,
                                                const float* __restrict__ scsh,
                                                const float* __restrict__ lng,
                                                const float* __restrict__ lnb,
                                                float* __restrict__ out) {
    __shared__ __align__(16) char SM2[32768 + 2048];
    uint16_t* aLDS  = (uint16_t*)SM2;            // [32][64][8] = 32KB
    float*    lnred = (float*)(SM2 + 32768);     // [16 waves][16 rows][2]
    const int mtile = blockIdx.x;
    const int tid = threadIdx.x;
    const int wave = tid >> 6;
    const int lane = tid & 63;
    const int q = lane >> 4, l15 = lane & 15;
    const int m0 = mtile*16;
    const int n0 = wave*32;

    // stage this mtile's A fragments: 2048 uint4
    {
        const uint4* hsrc = reinterpret_cast<const uint4*>(hfrag + (size_t)mtile*KT2*64*8);
        uint4* adst = reinterpret_cast<uint4*>(aLDS);
        adst[tid]        = hsrc[tid];
        adst[tid + 1024] = hsrc[tid + 1024];
    }
    __syncthreads();

    floatx4 acc[2] = {};
    #pragma unroll
    for (int kk = 0; kk < 32; ++kk) {
        short8 a = *reinterpret_cast<const short8*>(aLDS + (kk*64 + lane)*8);
        #pragma unroll
        for (int nf = 0; nf < 2; ++nf) {
            int ct = (n0 >> 4) + nf;
            short8 bfr = *reinterpret_cast<const short8*>(
                w2bf + ((size_t)(ct*32 + kk)*64 + lane)*8);
            acc[nf] = __builtin_amdgcn_mfma_f32_16x16x32_bf16(a, bfr, acc[nf], 0, 0, 0);
        }
    }
    // v = acc + b2 + BN(x); keep in registers, accumulate LN partials
    float s_pt[4]  = {0.f,0.f,0.f,0.f};
    float s2_pt[4] = {0.f,0.f,0.f,0.f};
    #pragma unroll
    for (int r = 0; r < 4; ++r) {
        int row = m0 + q*4 + r;
        int d = row % DD;
        float scv = scsh[d], shv = scsh[DD + d];
        #pragma unroll
        for (int nf = 0; nf < 2; ++nf) {
            int col = n0 + nf*16 + l15;
            float v = acc[nf][r] + b2[col] + x[(size_t)row*TT + col]*scv + shv;
            acc[nf][r] = v;
            s_pt[r]  += v;
            s2_pt[r] += v*v;
        }
    }
    #pragma unroll
    for (int o = 1; o < 16; o <<= 1) {
        #pragma unroll
        for (int r = 0; r < 4; ++r) {
            s_pt[r]  += __shfl_xor(s_pt[r],  o, 64);
            s2_pt[r] += __shfl_xor(s2_pt[r], o, 64);
        }
    }
    if (l15 == 0) {
        #pragma unroll
        for (int r = 0; r < 4; ++r) {
            lnred[(wave*16 + q*4 + r)*2]     = s_pt[r];
            lnred[(wave*16 + q*4 + r)*2 + 1] = s2_pt[r];
        }
    }
    __syncthreads();
    #pragma unroll
    for (int r = 0; r < 4; ++r) {
        int rloc = q*4 + r;
        float s1 = 0.f, s2 = 0.f;
        #pragma unroll
        for (int w = 0; w < 16; ++w) {
            s1 += lnred[(w*16 + rloc)*2];
            s2 += lnred[(w*16 + rloc)*2 + 1];
        }
        const float invT = 1.0f / (float)TT;
        float mu  = s1 * invT;
        float var = s2 * invT - mu*mu;
        float rs  = rsqrtf(var + 1e-5f);
        int row = m0 + rloc;
        #pragma unroll
        for (int nf = 0; nf < 2; ++nf) {
            int col = n0 + nf*16 + l15;
            out[(size_t)row*TT + col] = (acc[nf][r] - mu)*rs*lng[col] + lnb[col];
        }
    }
}

extern "C" void kernel_launch(void* const* d_in, const int* in_sizes, int n_in,
                              void* d_out, int out_size, void* d_ws, size_t ws_size,
                              hipStream_t stream) {
    (void)in_sizes; (void)n_in; (void)out_size; (void)ws_size;
    const float* residual = (const float*)d_in[0];
    const float* bng = (const float*)d_in[1];
    const float* bnb = (const float*)d_in[2];
    const float* lng = (const float*)d_in[3];
    const float* lnb = (const float*)d_in[4];
    const float* W1  = (const float*)d_in[5];
    const float* b1  = (const float*)d_in[6];
    const float* W2  = (const float*)d_in[7];
    const float* b2  = (const float*)d_in[8];
    float* out = (float*)d_out;
    char* ws = (char*)d_ws;
    float*    x     = (float*)(ws + WSOFF_X);
    float*    A     = (float*)(ws + WSOFF_A);
    uint16_t* hfrag = (uint16_t*)(ws + WSOFF_HFRAG);
    uint16_t* w1bf  = (uint16_t*)(ws + WSOFF_W1BF);
    uint16_t* w2bf  = (uint16_t*)(ws + WSOFF_W2BF);
    float*    ps    = (float*)(ws + WSOFF_PS);
    float*    ps2   = (float*)(ws + WSOFF_PS2);
    float*    scsh  = (float*)(ws + WSOFF_SCSH);

    k_pre  <<<512, 256, 0, stream>>>(residual, W1, W2, A, w1bf, w2bf);
    k_attn <<<512, 256, 0, stream>>>(residual, A, x, ps, ps2);
    k_gemm1<<<dim3(96, 4), 512, 0, stream>>>(x, ps, ps2, bng, bnb, w1bf, b1, hfrag, scsh);
    k_gemm2<<<96, 1024, 0, stream>>>(hfrag, w2bf, b2, x, scsh, lng, lnb, out);
}

// Round 4
// 112.105 us; speedup vs baseline: 1.1956x; 1.1724x over previous
//
#include <hip/hip_runtime.h>
#include <math.h>
#include <stdint.h>

#define BB 16
#define DD 96
#define TT 512
#define HH 1024
#define NROW (BB*DD)
#define KT2 (HH/32)   // 32 k-tiles of 32 for gemm2

typedef __attribute__((ext_vector_type(4))) float floatx4;
typedef __attribute__((ext_vector_type(8))) short short8;

// ---------------- ws layout (bytes) ----------------
// x fp32 (3MB) | hfrag bf16 (3MB) | w1bf (1MB) | w2bf (1MB) | ps (48KB) | ps2 (48KB) | s (6KB)
#define WSOFF_X     0u
#define WSOFF_HFRAG 3145728u
#define WSOFF_W1BF  6291456u
#define WSOFF_W2BF  7340032u
#define WSOFF_PS    8388608u
#define WSOFF_PS2   8437760u
#define WSOFF_S     8486912u

__device__ __forceinline__ uint16_t f2bf(float v) {
    uint32_t u = __float_as_uint(v);
    uint32_t r = 0x7fffu + ((u >> 16) & 1u);
    return (uint16_t)((u + r) >> 16);
}

// K1: blocks 0..95: rowsums (16 rows each, 4 independent chains per wave).
//     blocks 96..511: weight swizzle.
__global__ __launch_bounds__(256) void k_pre(const float* __restrict__ residual,
                                             const float* __restrict__ W1,
                                             const float* __restrict__ W2,
                                             float* __restrict__ s,
                                             uint16_t* __restrict__ w1bf,
                                             uint16_t* __restrict__ w2bf) {
    const int bid = blockIdx.x;
    const int tid = threadIdx.x;
    const int wave = tid >> 6;
    const int lane = tid & 63;
    const int q = lane >> 4, l15 = lane & 15;

    if (bid < 96) {
        int row0 = bid*16 + wave*4;
        float acc[4] = {0.f, 0.f, 0.f, 0.f};
        #pragma unroll
        for (int cc = 0; cc < 4; ++cc) {
            const float* p = residual + (size_t)(row0 + cc)*TT;
            #pragma unroll
            for (int u = 0; u < TT/64; ++u) acc[cc] += p[lane + u*64];
        }
        #pragma unroll
        for (int o = 32; o > 0; o >>= 1) {
            #pragma unroll
            for (int cc = 0; cc < 4; ++cc) acc[cc] += __shfl_down(acc[cc], o, 64);
        }
        if (lane == 0) {
            #pragma unroll
            for (int cc = 0; cc < 4; ++cc) s[row0 + cc] = acc[cc];
        }
    } else {
        int wgid = (bid - 96)*4 + wave;
        const int nw = (512 - 96)*4;
        for (int u = wgid; u < 2048; u += nw) {
            const float* W; uint16_t* ob; int KT, N, b;
            if (u < 1024) { W = W1; ob = w1bf; KT = 16; N = 1024; b = u; }
            else          { W = W2; ob = w2bf; KT = 32; N = 512;  b = u - 1024; }
            int tile_n = b / KT, tile_k = b % KT;
            const float* src = W + (size_t)(tile_k*32 + q*8)*N + tile_n*16 + l15;
            uint16_t tmp[8];
            #pragma unroll
            for (int j = 0; j < 8; ++j) tmp[j] = f2bf(src[(size_t)j*N]);
            uint16_t* dst = ob + ((size_t)b*64 + lane)*8;
            *reinterpret_cast<ushort4*>(dst)     = *reinterpret_cast<ushort4*>(&tmp[0]);
            *reinterpret_cast<ushort4*>(dst + 4) = *reinterpret_cast<ushort4*>(&tmp[4]);
        }
    }
}

// K2: softmax rows computed in-LDS from s, then x = A@r + r, with BN partial sums.
__global__ __launch_bounds__(256) void k_attn(const float* __restrict__ residual,
                                              const float* __restrict__ s,
                                              float* __restrict__ x,
                                              float* __restrict__ ps,
                                              float* __restrict__ ps2) {
    __shared__ float rlds[DD*64];      // 24KB
    __shared__ float slds[DD];         // raw rowsums for this batch
    __shared__ float aLDS[24*DD];      // 24 softmax rows (this block's ig-slice), 9KB
    const int u = blockIdx.x;           // 512 = 16 b * 8 chunk * 4 ig
    const int b = u >> 5, chunk = (u >> 2) & 7, ig = u & 3;
    const int tid = threadIdx.x;
    const int wave = tid >> 6;
    const int lane = tid & 63;

    const float4* rb4 = reinterpret_cast<const float4*>(residual + (size_t)b*DD*TT);
    float4* rl4 = reinterpret_cast<float4*>(rlds);
    #pragma unroll
    for (int sx = 0; sx < 6; ++sx) {
        int idx = tid + sx*256;
        int i = idx >> 4, t4 = idx & 15;
        rl4[idx] = rb4[(size_t)i*(TT/4) + chunk*16 + t4];
    }
    if (tid < DD) slds[tid] = s[b*DD + tid];
    __syncthreads();

    // each wave computes softmax for its 6 rows (global rows ig*24 + wave*6 + rr)
    const float c = 1.0f / (512.0f * 22.627416997969522f);  // T^-1.5
    float sj_lo = slds[lane];
    float sj_hi = (lane < 32) ? slds[64 + lane] : 0.f;
    #pragma unroll
    for (int rr = 0; rr < 6; ++rr) {
        int iloc = wave*6 + rr;
        float si = slds[ig*24 + iloc] * c;
        float v1 = si * sj_lo;
        float v2 = (lane < 32) ? si * sj_hi : -1e30f;
        float m = fmaxf(v1, v2);
        #pragma unroll
        for (int o = 1; o < 64; o <<= 1) m = fmaxf(m, __shfl_xor(m, o, 64));
        float p1 = __expf(v1 - m);
        float p2 = (lane < 32) ? __expf(v2 - m) : 0.f;
        float sum = p1 + p2;
        #pragma unroll
        for (int o = 1; o < 64; o <<= 1) sum += __shfl_xor(sum, o, 64);
        float inv = 1.0f / sum;
        aLDS[iloc*DD + lane] = p1 * inv;
        if (lane < 32) aLDS[iloc*DD + 64 + lane] = p2 * inv;
    }
    // aLDS rows are wave-local (written and read by the same wave) -> no barrier needed

    int i0 = ig*24 + wave*6;
    float acc[6];
    #pragma unroll
    for (int rr = 0; rr < 6; ++rr) acc[rr] = rlds[(i0+rr)*64 + lane];
    #pragma unroll 4
    for (int j4 = 0; j4 < DD/4; ++j4) {
        float4 a[6];
        #pragma unroll
        for (int rr = 0; rr < 6; ++rr)
            a[rr] = *reinterpret_cast<const float4*>(&aLDS[(wave*6+rr)*DD + j4*4]);
        float rv[4];
        #pragma unroll
        for (int uu = 0; uu < 4; ++uu) rv[uu] = rlds[(j4*4+uu)*64 + lane];
        #pragma unroll
        for (int rr = 0; rr < 6; ++rr) {
            acc[rr] = fmaf(a[rr].x, rv[0], acc[rr]);
            acc[rr] = fmaf(a[rr].y, rv[1], acc[rr]);
            acc[rr] = fmaf(a[rr].z, rv[2], acc[rr]);
            acc[rr] = fmaf(a[rr].w, rv[3], acc[rr]);
        }
    }
    #pragma unroll
    for (int rr = 0; rr < 6; ++rr) {
        float v = acc[rr];
        x[((size_t)b*DD + i0 + rr)*TT + chunk*64 + lane] = v;
        float s1 = v, s2 = v*v;
        #pragma unroll
        for (int o = 32; o > 0; o >>= 1) {
            s1 += __shfl_down(s1, o, 64);
            s2 += __shfl_down(s2, o, 64);
        }
        if (lane == 0) {
            int d = i0 + rr;
            ps [d*128 + b*8 + chunk] = s1;
            ps2[d*128 + b*8 + chunk] = s2;
        }
    }
}

// Inline BN finalize for the 16 channels of one mtile. scs[16][2] in LDS.
// Thread group dg = tid>>4 (16 threads each) handles channel d=(m0+dg)%DD.
__device__ __forceinline__ void bn_finalize16(const float* __restrict__ ps,
                                              const float* __restrict__ ps2,
                                              const float* __restrict__ bng,
                                              const float* __restrict__ bnb,
                                              int m0, int tid, float* scs) {
    if (tid < 256) {
        int dg = tid >> 4, uu = tid & 15;
        int d = (m0 + dg) % DD;
        const float4* p1 = reinterpret_cast<const float4*>(ps  + d*128 + uu*8);
        const float4* p2 = reinterpret_cast<const float4*>(ps2 + d*128 + uu*8);
        float4 a0 = p1[0], a1 = p1[1];
        float4 b0 = p2[0], b1 = p2[1];
        float s1 = a0.x+a0.y+a0.z+a0.w + a1.x+a1.y+a1.z+a1.w;
        float s2 = b0.x+b0.y+b0.z+b0.w + b1.x+b1.y+b1.z+b1.w;
        #pragma unroll
        for (int o = 1; o < 16; o <<= 1) {
            s1 += __shfl_xor(s1, o, 16);
            s2 += __shfl_xor(s2, o, 16);
        }
        if (uu == 0) {
            const float invn = 1.0f / (float)(BB*TT);
            float mu  = s1 * invn;
            float var = s2 * invn - mu*mu;
            float rs  = rsqrtf(var + 1e-5f);
            float scv = rs * bng[d];
            scs[dg*2]     = scv;
            scs[dg*2 + 1] = bnb[d] - mu*scv;
        }
    }
}

// K3: gemm1 with inline BN. grid (96, 8) x 256.  M=16, N=128 per block.
__global__ __launch_bounds__(256) void k_gemm1(const float* __restrict__ x,
                                               const float* __restrict__ ps,
                                               const float* __restrict__ ps2,
                                               const float* __restrict__ bng,
                                               const float* __restrict__ bnb,
                                               const uint16_t* __restrict__ w1bf,
                                               const float* __restrict__ b1,
                                               uint16_t* __restrict__ hfrag) {
    __shared__ __align__(16) uint16_t fragA[16*64*8];   // 16KB
    __shared__ __align__(16) uint16_t cs[16][136];
    __shared__ float scs[32];
    const int mtile = blockIdx.x;
    const int m0 = mtile*16;
    const int tid = threadIdx.x;
    const int wave = tid >> 6;
    const int lane = tid & 63;
    const int q = lane >> 4, l15 = lane & 15;

    bn_finalize16(ps, ps2, bng, bnb, m0, tid, scs);
    __syncthreads();

    // build bf16 A-fragments (BN applied inline): 1024 slots, 4 per thread
    #pragma unroll
    for (int r4 = 0; r4 < 4; ++r4) {
        int pi = tid + r4*256;
        int kk = pi >> 6, pl = pi & 63;
        int pq = pl >> 4, pr = pl & 15;
        float scv = scs[pr*2], shv = scs[pr*2 + 1];
        const float* xp = x + (size_t)(m0 + pr)*TT + kk*32 + pq*8;
        float4 v0 = *reinterpret_cast<const float4*>(xp);
        float4 v1 = *reinterpret_cast<const float4*>(xp + 4);
        ushort4 o0, o1;
        o0.x = f2bf(v0.x*scv + shv); o0.y = f2bf(v0.y*scv + shv);
        o0.z = f2bf(v0.z*scv + shv); o0.w = f2bf(v0.w*scv + shv);
        o1.x = f2bf(v1.x*scv + shv); o1.y = f2bf(v1.y*scv + shv);
        o1.z = f2bf(v1.z*scv + shv); o1.w = f2bf(v1.w*scv + shv);
        uint16_t* fp = fragA + ((size_t)kk*64 + pl)*8;
        *reinterpret_cast<ushort4*>(fp)     = o0;
        *reinterpret_cast<ushort4*>(fp + 4) = o1;
    }
    __syncthreads();

    const int n0 = blockIdx.y*128 + wave*32;
    floatx4 acc4[2] = {};
    const uint16_t* b0p = w1bf + ((size_t)((n0>>4)    )*16*64 + lane)*8;
    const uint16_t* b1p = w1bf + ((size_t)((n0>>4) + 1)*16*64 + lane)*8;
    #pragma unroll
    for (int kk = 0; kk < 16; ++kk) {
        short8 a  = *reinterpret_cast<const short8*>(fragA + (kk*64 + lane)*8);
        short8 bb0 = *reinterpret_cast<const short8*>(b0p + kk*512);
        short8 bb1 = *reinterpret_cast<const short8*>(b1p + kk*512);
        acc4[0] = __builtin_amdgcn_mfma_f32_16x16x32_bf16(a, bb0, acc4[0], 0, 0, 0);
        acc4[1] = __builtin_amdgcn_mfma_f32_16x16x32_bf16(a, bb1, acc4[1], 0, 0, 0);
    }
    #pragma unroll
    for (int nf = 0; nf < 2; ++nf) {
        int coll = wave*32 + nf*16 + l15;
        float bias = b1[blockIdx.y*128 + coll];
        #pragma unroll
        for (int r = 0; r < 4; ++r) {
            float v = acc4[nf][r] + bias;
            float gl = 0.5f * v * (1.0f + erff(v * 0.7071067811865475f));
            cs[q*4 + r][coll] = f2bf(gl);
        }
    }
    __syncthreads();
    {
        int cchunk = wave;   // 4 waves -> 4 k-chunks of this block's 128-col slice
        const uint4* srcp = reinterpret_cast<const uint4*>(&cs[l15][cchunk*32 + q*8]);
        size_t chunk = (size_t)mtile*KT2 + (blockIdx.y*4 + cchunk);
        reinterpret_cast<uint4*>(hfrag)[chunk*64 + lane] = *srcp;
    }
}

// K4: gemm2 + bias + BN(x) residual (fp32) -> y (=out).  grid (96, 4) x 256.
__global__ __launch_bounds__(256) void k_gemm2(const uint16_t* __restrict__ hfrag,
                                               const uint16_t* __restrict__ w2bf,
                                               const float* __restrict__ b2,
                                               const float* __restrict__ x,
                                               const float* __restrict__ ps,
                                               const float* __restrict__ ps2,
                                               const float* __restrict__ bng,
                                               const float* __restrict__ bnb,
                                               float* __restrict__ y) {
    __shared__ float scs[32];
    const int mtile = blockIdx.x;
    const int m0 = mtile*16;
    const int tid = threadIdx.x;
    const int wave = tid >> 6;
    const int lane = tid & 63;
    const int q = lane >> 4, l15 = lane & 15;
    const int n0 = blockIdx.y*128 + wave*32;

    bn_finalize16(ps, ps2, bng, bnb, m0, tid, scs);
    __syncthreads();

    floatx4 acc[2] = {};
    const uint16_t* ap  = hfrag + ((size_t)mtile*KT2*64 + lane)*8;
    const uint16_t* b0p = w2bf + ((size_t)((n0>>4)    )*32*64 + lane)*8;
    const uint16_t* b1p = w2bf + ((size_t)((n0>>4) + 1)*32*64 + lane)*8;
    #pragma unroll
    for (int kk = 0; kk < 32; ++kk) {
        short8 a  = *reinterpret_cast<const short8*>(ap  + kk*512);
        short8 bb0 = *reinterpret_cast<const short8*>(b0p + kk*512);
        short8 bb1 = *reinterpret_cast<const short8*>(b1p + kk*512);
        acc[0] = __builtin_amdgcn_mfma_f32_16x16x32_bf16(a, bb0, acc[0], 0, 0, 0);
        acc[1] = __builtin_amdgcn_mfma_f32_16x16x32_bf16(a, bb1, acc[1], 0, 0, 0);
    }
    #pragma unroll
    for (int nf = 0; nf < 2; ++nf) {
        int col = n0 + nf*16 + l15;
        float bias = b2[col];
        #pragma unroll
        for (int r = 0; r < 4; ++r) {
            int rloc = q*4 + r;
            int row = m0 + rloc;
            float xb = x[(size_t)row*TT + col]*scs[rloc*2] + scs[rloc*2 + 1];
            y[(size_t)row*TT + col] = acc[nf][r] + bias + xb;
        }
    }
}

// K5: LayerNorm per row over T=512, in-place on out.
__global__ __launch_bounds__(64) void k_ln(float* __restrict__ y,
                                           const float* __restrict__ lng,
                                           const float* __restrict__ lnb) {
    int row = blockIdx.x;
    int lane = threadIdx.x;
    float4* p = reinterpret_cast<float4*>(y + (size_t)row*TT);
    float4 v0 = p[lane*2], v1 = p[lane*2 + 1];
    float s  = v0.x+v0.y+v0.z+v0.w + v1.x+v1.y+v1.z+v1.w;
    float s2 = v0.x*v0.x+v0.y*v0.y+v0.z*v0.z+v0.w*v0.w
             + v1.x*v1.x+v1.y*v1.y+v1.z*v1.z+v1.w*v1.w;
    #pragma unroll
    for (int o = 1; o < 64; o <<= 1) {
        s  += __shfl_xor(s,  o, 64);
        s2 += __shfl_xor(s2, o, 64);
    }
    float mu = s * (1.0f/TT);
    float var = s2 * (1.0f/TT) - mu*mu;
    float rs = rsqrtf(var + 1e-5f);
    const float4* g4 = reinterpret_cast<const float4*>(lng);
    const float4* b4 = reinterpret_cast<const float4*>(lnb);
    float4 g0 = g4[lane*2], g1 = g4[lane*2+1];
    float4 bb0 = b4[lane*2], bb1 = b4[lane*2+1];
    float4 o0, o1;
    o0.x = (v0.x-mu)*rs*g0.x + bb0.x;  o0.y = (v0.y-mu)*rs*g0.y + bb0.y;
    o0.z = (v0.z-mu)*rs*g0.z + bb0.z;  o0.w = (v0.w-mu)*rs*g0.w + bb0.w;
    o1.x = (v1.x-mu)*rs*g1.x + bb1.x;  o1.y = (v1.y-mu)*rs*g1.y + bb1.y;
    o1.z = (v1.z-mu)*rs*g1.z + bb1.z;  o1.w = (v1.w-mu)*rs*g1.w + bb1.w;
    p[lane*2] = o0;  p[lane*2+1] = o1;
}

extern "C" void kernel_launch(void* const* d_in, const int* in_sizes, int n_in,
                              void* d_out, int out_size, void* d_ws, size_t ws_size,
                              hipStream_t stream) {
    (void)in_sizes; (void)n_in; (void)out_size; (void)ws_size;
    const float* residual = (const float*)d_in[0];
    const float* bng = (const float*)d_in[1];
    const float* bnb = (const float*)d_in[2];
    const float* lng = (const float*)d_in[3];
    const float* lnb = (const float*)d_in[4];
    const float* W1  = (const float*)d_in[5];
    const float* b1  = (const float*)d_in[6];
    const float* W2  = (const float*)d_in[7];
    const float* b2  = (const float*)d_in[8];
    float* out = (float*)d_out;
    char* ws = (char*)d_ws;
    float*    x     = (float*)(ws + WSOFF_X);
    uint16_t* hfrag = (uint16_t*)(ws + WSOFF_HFRAG);
    uint16_t* w1bf  = (uint16_t*)(ws + WSOFF_W1BF);
    uint16_t* w2bf  = (uint16_t*)(ws + WSOFF_W2BF);
    float*    ps    = (float*)(ws + WSOFF_PS);
    float*    ps2   = (float*)(ws + WSOFF_PS2);
    float*    s     = (float*)(ws + WSOFF_S);

    k_pre  <<<512, 256, 0, stream>>>(residual, W1, W2, s, w1bf, w2bf);
    k_attn <<<512, 256, 0, stream>>>(residual, s, x, ps, ps2);
    k_gemm1<<<dim3(96, 8), 256, 0, stream>>>(x, ps, ps2, bng, bnb, w1bf, b1, hfrag);
    k_gemm2<<<dim3(96, 4), 256, 0, stream>>>(hfrag, w2bf, b2, x, ps, ps2, bng, bnb, out);
    k_ln   <<<NROW, 64, 0, stream>>>(out, lng, lnb);
}